// Round 10
// baseline (274.103 us; speedup 1.0000x reference)
//
#include <hip/hip_runtime.h>
#include <hip/hip_bf16.h>

// ---------------- problem constants ----------------
#define NB    2
#define NS    1024
#define NPTS  8192
#define NGROUP (NB*NS*4)   // 8192 groups

// ---------------- ws layout (float offsets) ----------------
enum : int {
  OFF_BW2  = 256,      // 8192 bf16: W2 folded, frag order
  OFF_W1Q  = 4352,     // 64 x float4 (w0,w1,w2,b) folded L1
  OFF_B2   = 8448,     // 128 f32
  OFF_BW3  = 8576,     // 32768 bf16: W3 folded, B-frag order
  OFF_B3   = 41344,    // 256 f32
  OFF_HB1  = 41600,    // 65536 bf16 head L1
  OFF_HB1B = 74368,
  OFF_HB2  = 74624,    // 65536 bf16 head L2 block-diag
  OFF_HB2B = 107392,
  OFF_HB3  = 107648,   // 16384 bf16 head L3
  OFF_HB3B = 115840,
  OFF_FEAT = 146688,            // 8192 * 64 * 3
  OFF_VP   = 1719552,           // 8192 * 256
  // overlaid into VP region (dead after group):
  OFF_PCX  = 1719552, OFF_PCY = 1735936, OFF_PCZ = 1752320,
  OFF_SEED = 1768704, OFF_ROT = 1774848,
  OFF_FLAG = 3824896,           // 1 int
  OFF_BCNT = 3824900,           // 4 ints: per-MT bucket counts
  OFF_BL   = 3824912,           // 4 x 8192 ints: per-MT group lists
  PREP_TOTAL = 189632 + 6144 + 18432 + 49152,  // = 263360
};

struct Ptrs { const void* p[25]; };

typedef __attribute__((ext_vector_type(8))) short bf16x8;
typedef __attribute__((ext_vector_type(4))) float f32x4;
typedef __attribute__((ext_vector_type(4))) unsigned u32x4;

template<typename T> struct LD;
template<> struct LD<float> {
  static __device__ __forceinline__ float get(const void* p, int i){ return ((const float*)p)[i]; }
};
template<> struct LD<__hip_bfloat16> {
  static __device__ __forceinline__ float get(const void* p, int i){ return __bfloat162float(((const __hip_bfloat16*)p)[i]); }
};

template<typename T>
__device__ __forceinline__ float bnscale(const void* bn, int C, int c){
  float g = LD<T>::get(bn, c);
  float v = LD<T>::get(bn, 3*C + c);
  return g / sqrtf(v + 1e-5f);
}

__device__ __forceinline__ unsigned short f2bf(float v){
  __hip_bfloat16 hb = __float2bfloat16(v);
  return *reinterpret_cast<unsigned short*>(&hb);
}

#if __has_builtin(__builtin_amdgcn_cvt_pk_bf16_f32)
typedef __attribute__((ext_vector_type(2))) __bf16 bf16x2_t;
__device__ __forceinline__ unsigned pk2bf(float a, float b){
  bf16x2_t r = __builtin_amdgcn_cvt_pk_bf16_f32(a, b);
  return *reinterpret_cast<unsigned*>(&r);
}
#else
__device__ __forceinline__ unsigned pk2bf(float a, float b){
  return (unsigned)f2bf(a) | ((unsigned)f2bf(b) << 16);
}
#endif

// ---------------- prep body: fold BN; swizzle weights; fp32 SoA geometry ----------------
template<typename T>
__device__ void prep_body(const Ptrs& in, float* __restrict__ ws, int i){
  if (i < 256) { int c = i>>2, d = i&3; float s = bnscale<T>(in.p[4],64,c);
    float v = (d<3) ? LD<T>::get(in.p[3], c*3+d)*s
                    : LD<T>::get(in.p[4],64+c) - LD<T>::get(in.p[4],2*64+c)*s;
    ws[OFF_W1Q+i] = v; return; }
  i -= 256;
  if (i < 8192) { // BW2: 128x64, KT=2
    int j = i&7, f = i>>3, lane = f&63, kn = f>>6, kt = kn&1, nt = kn>>1;
    int n = nt*16 + (lane&15), k = kt*32 + ((lane>>4)<<3) + j;
    float s = bnscale<T>(in.p[6],128,n);
    ((unsigned short*)(ws + OFF_BW2))[i] = f2bf(LD<T>::get(in.p[5], n*64+k)*s); return; }
  i -= 8192;
  if (i < 32768) { // BW3: 256x128, KT=4
    int j = i&7, f = i>>3, lane = f&63, kn = f>>6, kt = kn&3, nt = kn>>2;
    int n = nt*16 + (lane&15), k = kt*32 + ((lane>>4)<<3) + j;
    float s = bnscale<T>(in.p[8],256,n);
    ((unsigned short*)(ws + OFF_BW3))[i] = f2bf(LD<T>::get(in.p[7], n*128+k)*s); return; }
  i -= 32768;
  if (i < 128) { float s = bnscale<T>(in.p[6],128,i);
    ws[OFF_B2+i] = LD<T>::get(in.p[6],128+i) - LD<T>::get(in.p[6],2*128+i)*s; return; }
  i -= 128;
  if (i < 256) { float s = bnscale<T>(in.p[8],256,i);
    ws[OFF_B3+i] = LD<T>::get(in.p[8],256+i) - LD<T>::get(in.p[8],2*256+i)*s; return; }
  i -= 256;
  if (i < 65536) { // HB1
    int j = i&7, f = i>>3, lane = f&63, kn = f>>6, kt = kn&7, nt = kn>>3;
    int n = nt*16 + (lane&15), k = kt*32 + ((lane>>4)<<3) + j;
    float v;
    if (n < 128) v = LD<T>::get(in.p[9],  n*256+k)       * bnscale<T>(in.p[11],128,n);
    else         v = LD<T>::get(in.p[17], (n-128)*256+k) * bnscale<T>(in.p[19],128,n-128);
    ((unsigned short*)(ws + OFF_HB1))[i] = f2bf(v); return; }
  i -= 65536;
  if (i < 256) { int n = i; float v;
    if (n < 128) { float s = bnscale<T>(in.p[11],128,n);
      v = (LD<T>::get(in.p[10],n) - LD<T>::get(in.p[11],2*128+n))*s + LD<T>::get(in.p[11],128+n); }
    else { int m = n-128; float s = bnscale<T>(in.p[19],128,m);
      v = (LD<T>::get(in.p[18],m) - LD<T>::get(in.p[19],2*128+m))*s + LD<T>::get(in.p[19],128+m); }
    ws[OFF_HB1B+n] = v; return; }
  i -= 256;
  if (i < 65536) { // HB2 block-diagonal
    int j = i&7, f = i>>3, lane = f&63, kn = f>>6, kt = kn&7, nt = kn>>3;
    int n = nt*16 + (lane&15), k = kt*32 + ((lane>>4)<<3) + j;
    float v = 0.f;
    if (n < 128) { if (k < 128)  v = LD<T>::get(in.p[12], n*128+k)            * bnscale<T>(in.p[14],128,n); }
    else         { if (k >= 128) v = LD<T>::get(in.p[20], (n-128)*128+(k-128)) * bnscale<T>(in.p[22],128,n-128); }
    ((unsigned short*)(ws + OFF_HB2))[i] = f2bf(v); return; }
  i -= 65536;
  if (i < 256) { int n = i; float v;
    if (n < 128) { float s = bnscale<T>(in.p[14],128,n);
      v = (LD<T>::get(in.p[13],n) - LD<T>::get(in.p[14],2*128+n))*s + LD<T>::get(in.p[14],128+n); }
    else { int m = n-128; float s = bnscale<T>(in.p[22],128,m);
      v = (LD<T>::get(in.p[21],m) - LD<T>::get(in.p[22],2*128+m))*s + LD<T>::get(in.p[22],128+m); }
    ws[OFF_HB2B+n] = v; return; }
  i -= 256;
  if (i < 16384) { // HB3
    int j = i&7, f = i>>3, lane = f&63, kn = f>>6, kt = kn&7, nt = kn>>3;
    int n = nt*16 + (lane&15), k = kt*32 + ((lane>>4)<<3) + j;
    float v = 0.f;
    if (n < 36)      { if (k < 128)  v = LD<T>::get(in.p[15], n*128+k); }
    else if (n < 48) { if (k >= 128) v = LD<T>::get(in.p[23], (n-36)*128+(k-128)); }
    ((unsigned short*)(ws + OFF_HB3))[i] = f2bf(v); return; }
  i -= 16384;
  if (i < 64) { int n = i; float v = 0.f;
    if (n < 36) v = LD<T>::get(in.p[16], n);
    else if (n < 48) v = LD<T>::get(in.p[24], n-36);
    ws[OFF_HB3B+n] = v; return; }
  i -= 64;
  if (i < 6144)  { ws[OFF_SEED+i] = LD<T>::get(in.p[0], i); return; }
  i -= 6144;
  if (i < 18432) { ws[OFF_ROT+i] = LD<T>::get(in.p[2], i); return; }
  i -= 18432;
  { int arr = i >> 14, idx = i & 16383;
    ws[OFF_PCX + arr*16384 + idx] = LD<T>::get(in.p[1], idx*3 + arr); }
}

// ---------------- kernel 0: detect dtype + zero bucket counters + prep ----------------
__global__ __launch_bounds__(256) void prep_kernel(Ptrs in, float* __restrict__ ws){
  __shared__ int sf;
  const int t = threadIdx.x;
  if (t == 0) sf = 0;
  __syncthreads();
  int loc = 0;
  const uint4* w3r = (const uint4*)in.p[7];
#pragma unroll
  for (int k = 0; k < 8; ++k) {
    uint4 u = w3r[t + k*256];
    loc |= ((u.x & 0x7F80u) == 0x7F80u) | (((u.x>>16) & 0x7F80u) == 0x7F80u);
    loc |= ((u.y & 0x7F80u) == 0x7F80u) | (((u.y>>16) & 0x7F80u) == 0x7F80u);
    loc |= ((u.z & 0x7F80u) == 0x7F80u) | (((u.z>>16) & 0x7F80u) == 0x7F80u);
    loc |= ((u.w & 0x7F80u) == 0x7F80u) | (((u.w>>16) & 0x7F80u) == 0x7F80u);
  }
  if (loc) atomicOr(&sf, 1);
  __syncthreads();
  const int isf32 = sf;
  const int i = blockIdx.x*256 + t;
  if (blockIdx.x == 0) {
    if (t == 0) ((int*)(ws + OFF_FLAG))[0] = isf32;
    if (t < 4)  ((int*)(ws + OFF_BCNT))[t] = 0;
  }
  if (i >= PREP_TOTAL) return;
  if (isf32) prep_body<float>(in, ws, i);
  else       prep_body<__hip_bfloat16>(in, ws, i);
}

// ---------------- group: 2 seeds/block, 2 waves/seed, fill-to-64 + MT bucketing ----------------
__global__ __launch_bounds__(256) void group_kernel(float* __restrict__ ws){
#pragma clang fp contract(off)
  __shared__ float scratch[2][2][4][192];   // [seed][half][bin][slot*3]
  __shared__ int   cl[2][2][4];
  __shared__ float p0s[2][3];
  const int t = threadIdx.x;
  const int wave = t >> 6, lane = t & 63;
  const int s = wave >> 1, half = wave & 1;
  const int seedIdx = blockIdx.x*2 + s;
  const int b = seedIdx >> 10;
  const float sx = ws[OFF_SEED + seedIdx*3+0];
  const float sy = ws[OFF_SEED + seedIdx*3+1];
  const float sz = ws[OFF_SEED + seedIdx*3+2];
  const float r00=ws[OFF_ROT+seedIdx*9+0], r01=ws[OFF_ROT+seedIdx*9+1], r02=ws[OFF_ROT+seedIdx*9+2];
  const float r10=ws[OFF_ROT+seedIdx*9+3], r11=ws[OFF_ROT+seedIdx*9+4], r12=ws[OFF_ROT+seedIdx*9+5];
  const float r20=ws[OFF_ROT+seedIdx*9+6], r21=ws[OFF_ROT+seedIdx*9+7], r22=ws[OFF_ROT+seedIdx*9+8];
  const float* px = ws + OFF_PCX + b*8192;
  const float* py = ws + OFF_PCY + b*8192;
  const float* pz = ws + OFF_PCZ + b*8192;
  if (half == 0 && lane == 0) {
    float e0 = px[0] - sx, e1 = py[0] - sy, e2 = pz[0] - sz;
    p0s[s][0] = e0*r00 + e1*r10 + e2*r20;
    p0s[s][1] = e0*r01 + e1*r11 + e2*r21;
    p0s[s][2] = e0*r02 + e1*r12 + e2*r22;
  }
  float* s0 = scratch[s][half][0];
  float* s1 = scratch[s][half][1];
  float* s2 = scratch[s][half][2];
  float* s3 = scratch[s][half][3];
  int c0n=0, c1n=0, c2n=0, c3n=0;
  const int basept = half*4096;
  const unsigned long long pm = (1ull << lane) - 1ull;

  auto scan = [&](float x, float y, float z){
    float e0 = x - sx, e1 = y - sy, e2 = z - sz;
    float rx = e0*r00 + e1*r10 + e2*r20;
    float ry = e0*r01 + e1*r11 + e2*r21;
    float rz = e0*r02 + e1*r12 + e2*r22;
    float r2 = ry*ry + rz*rz;
    const bool mb = (rx > -0.2f) && (r2 < 0.09f);
    { bool m = mb && (rx < 0.1f); unsigned long long bal = __ballot(m);
      if (bal) { int slot = c0n + __popcll(bal & pm);
        if (m && slot < 64) { s0[slot*3]=rx; s0[slot*3+1]=ry; s0[slot*3+2]=rz; }
        c0n += __popcll(bal); } }
    { bool m = mb && (rx < 0.2f); unsigned long long bal = __ballot(m);
      if (bal) { int slot = c1n + __popcll(bal & pm);
        if (m && slot < 64) { s1[slot*3]=rx; s1[slot*3+1]=ry; s1[slot*3+2]=rz; }
        c1n += __popcll(bal); } }
    { bool m = mb && (rx < 0.3f); unsigned long long bal = __ballot(m);
      if (bal) { int slot = c2n + __popcll(bal & pm);
        if (m && slot < 64) { s2[slot*3]=rx; s2[slot*3+1]=ry; s2[slot*3+2]=rz; }
        c2n += __popcll(bal); } }
    { bool m = mb && (rx < 0.4f); unsigned long long bal = __ballot(m);
      if (bal) { int slot = c3n + __popcll(bal & pm);
        if (m && slot < 64) { s3[slot*3]=rx; s3[slot*3+1]=ry; s3[slot*3+2]=rz; }
        c3n += __popcll(bal); } }
  };

  for (int c = 0; c < 64; c += 2) {
    const int i0 = basept + c*64 + lane;
    float xA = px[i0],    yA = py[i0],    zA = pz[i0];
    float xB = px[i0+64], yB = py[i0+64], zB = pz[i0+64];
    scan(xA, yA, zA);
    scan(xB, yB, zB);
  }
  if (lane == 0) { cl[s][half][0]=c0n; cl[s][half][1]=c1n; cl[s][half][2]=c2n; cl[s][half][3]=c3n; }
  __syncthreads();
  // merge + fill all 64 slots
  for (int idx = t; idx < 512; idx += 256) {
    const int ss = idx >> 8, bin = (idx >> 6) & 3, slot = idx & 63;
    int ca = cl[ss][0][bin]; if (ca > 64) ca = 64;
    int cb = cl[ss][1][bin];
    const float* A = scratch[ss][0][bin];
    const float* B = scratch[ss][1][bin];
    float fx, fy, fz;
    if (slot < ca)              { fx=A[slot*3]; fy=A[slot*3+1]; fz=A[slot*3+2]; }
    else if (slot - ca < cb)    { int q = slot-ca; fx=B[q*3]; fy=B[q*3+1]; fz=B[q*3+2]; }
    else if (ca > 0)            { fx=A[0]; fy=A[1]; fz=A[2]; }
    else if (cb > 0)            { fx=B[0]; fy=B[1]; fz=B[2]; }
    else                        { fx=p0s[ss][0]; fy=p0s[ss][1]; fz=p0s[ss][2]; }
    const int g = (blockIdx.x*2 + ss)*4 + bin;
    float* fo = ws + OFF_FEAT + g*192;
    fo[slot*3+0]=fx; fo[slot*3+1]=fy; fo[slot*3+2]=fz;
  }
  // MT bucket append (one lane per (seed,bin))
  if (t < 8) {
    const int ss = t >> 2, bin = t & 3;
    int tot = cl[ss][0][bin] + cl[ss][1][bin];
    if (tot > 64) tot = 64;
    if (tot < 1)  tot = 1;
    const int mt = (tot + 15) >> 4;     // 1..4
    const int g = (blockIdx.x*2 + ss)*4 + bin;
    int w = atomicAdd(&((int*)(ws + OFF_BCNT))[mt-1], 1);
    if (w < 8192) ((int*)(ws + OFF_BL))[(mt-1)*8192 + w] = g;
  }
}

// ---------------- mlp body: MTS sample-tiles (static), role-swapped L2 ----------------
template<int MTS>
__device__ __forceinline__ void mlp_body(float* __restrict__ ws, unsigned short* __restrict__ h2,
                                         const float* __restrict__ wq,
                                         int lane, int quad, int l15, int nhalf, int g){
  const float* feat = ws + OFF_FEAT + g*192;
  float fx[MTS], fy[MTS], fz[MTS];
#pragma unroll
  for (int Nt = 0; Nt < MTS; ++Nt) {
    const int sm = Nt*16 + l15;
    fx[Nt] = feat[sm*3+0]; fy[Nt] = feat[sm*3+1]; fz[Nt] = feat[sm*3+2];
  }
  bf16x8 b1[MTS][2];
#pragma unroll
  for (int kt = 0; kt < 2; ++kt) {
    f32x4 w[8];
#pragma unroll
    for (int j = 0; j < 8; ++j) w[j] = *(const f32x4*)(wq + (kt*32 + quad*8 + j)*4);
#pragma unroll
    for (int Nt = 0; Nt < MTS; ++Nt) {
      const float x0 = fx[Nt], x1 = fy[Nt], x2 = fz[Nt];
      u32x4 p;
#pragma unroll
      for (int jp = 0; jp < 4; ++jp) {
        const f32x4 wa = w[2*jp], wb = w[2*jp+1];
        const float v0 = fmaxf(wa[3] + x0*wa[0] + x1*wa[1] + x2*wa[2], 0.f);
        const float v1 = fmaxf(wb[3] + x0*wb[0] + x1*wb[1] + x2*wb[2], 0.f);
        p[jp] = pk2bf(v0, v1);
      }
      b1[Nt][kt] = __builtin_bit_cast(bf16x8, p);
    }
  }
  const bf16x8* BW2 = (const bf16x8*)(ws + OFF_BW2);
#pragma unroll
  for (int mt4 = 0; mt4 < 4; ++mt4) {
    const int Mt = nhalf*4 + mt4;
    const f32x4 bias4 = *(const f32x4*)(ws + OFF_B2 + Mt*16 + quad*4);
    f32x4 acc[MTS];
#pragma unroll
    for (int Nt = 0; Nt < MTS; ++Nt) acc[Nt] = bias4;
#pragma unroll
    for (int kt = 0; kt < 2; ++kt) {
      const bf16x8 aw = BW2[(Mt*2+kt)*64 + lane];
#pragma unroll
      for (int Nt = 0; Nt < MTS; ++Nt)
        acc[Nt] = __builtin_amdgcn_mfma_f32_16x16x32_bf16(aw, b1[Nt][kt], acc[Nt], 0, 0, 0);
    }
#pragma unroll
    for (int Nt = 0; Nt < MTS; ++Nt) {
      const unsigned lo = pk2bf(fmaxf(acc[Nt][0],0.f), fmaxf(acc[Nt][1],0.f));
      const unsigned hi = pk2bf(fmaxf(acc[Nt][2],0.f), fmaxf(acc[Nt][3],0.f));
      uint2* dst = (uint2*)&h2[(Nt*16 + l15)*136 + Mt*16 + quad*4];
      *dst = make_uint2(lo, hi);
    }
  }
  __syncthreads();
  bf16x8 a2[MTS][4];
#pragma unroll
  for (int mt = 0; mt < MTS; ++mt)
#pragma unroll
    for (int kt = 0; kt < 4; ++kt)
      a2[mt][kt] = *(const bf16x8*)&h2[(mt*16 + l15)*136 + kt*32 + quad*8];
  const bf16x8* BW3 = (const bf16x8*)(ws + OFF_BW3);
  float vpv[8];
#pragma unroll
  for (int nt8 = 0; nt8 < 8; ++nt8) {
    const int nt = nhalf*8 + nt8;
    const int n = nt*16 + l15;
    const float bias = ws[OFF_B3 + n];
    f32x4 acc[MTS];
#pragma unroll
    for (int mt = 0; mt < MTS; ++mt) acc[mt] = (f32x4){bias, bias, bias, bias};
#pragma unroll
    for (int kt = 0; kt < 4; ++kt) {
      const bf16x8 b = BW3[(nt*4+kt)*64 + lane];
#pragma unroll
      for (int mt = 0; mt < MTS; ++mt)
        acc[mt] = __builtin_amdgcn_mfma_f32_16x16x32_bf16(a2[mt][kt], b, acc[mt], 0, 0, 0);
    }
    float mx = 0.f;   // relu >= 0: rows [V, MTS*16) are fill duplicates, safe
#pragma unroll
    for (int mt = 0; mt < MTS; ++mt)
      mx = fmaxf(mx, fmaxf(fmaxf(acc[mt][0], acc[mt][1]), fmaxf(acc[mt][2], acc[mt][3])));
    mx = fmaxf(mx, __shfl_xor(mx, 16, 64));
    mx = fmaxf(mx, __shfl_xor(mx, 32, 64));
    vpv[nt8] = mx;
  }
  if (quad == 0) {
    float* vp = ws + OFF_VP + g*256 + nhalf*128;
#pragma unroll
    for (int nt8 = 0; nt8 < 8; ++nt8) vp[nt8*16 + l15] = vpv[nt8];
  }
}

// ---------------- kernel 2: worklist-dispatched SharedMLP ----------------
// grid 16384: blk>>12 = MT variant (0..3), blk&4095 = pair index into its list.
__global__ __launch_bounds__(256) void mlp_kernel(float* __restrict__ ws){
  __shared__ unsigned short h2s[2][64*136];
  __shared__ float w1q[4][256];
  const int blk = blockIdx.x;
  const int v = blk >> 12;                 // 0..3 -> MT = v+1
  const int pairIdx = blk & 4095;
  int cnt = ((const volatile int*)(ws + OFF_BCNT))[v];
  if (cnt > 8192) cnt = 8192;
  if (pairIdx*2 >= cnt) return;
  const int* lst = (const int*)(ws + OFF_BL) + v*8192;
  const int g0 = lst[pairIdx*2];
  const int g1 = (pairIdx*2+1 < cnt) ? lst[pairIdx*2+1] : g0;
  const int t = threadIdx.x;
  const int wave = t >> 6, lane = t & 63;
  const int quad = lane >> 4, l15 = lane & 15;
  const int grp = wave >> 1, nhalf = wave & 1;
  const int g = grp ? g1 : g0;
  for (int i = t; i < 1024; i += 256) w1q[i>>8][i&255] = ws[OFF_W1Q + (i&255)];
  __syncthreads();
  unsigned short* h2 = h2s[grp];
  const float* wq = w1q[quad];
  switch (v) {
    case 0: mlp_body<1>(ws, h2, wq, lane, quad, l15, nhalf, g); break;
    case 1: mlp_body<2>(ws, h2, wq, lane, quad, l15, nhalf, g); break;
    case 2: mlp_body<3>(ws, h2, wq, lane, quad, l15, nhalf, g); break;
    default: mlp_body<4>(ws, h2, wq, lane, quad, l15, nhalf, g); break;
  }
}

// ---------------- kernel 3: heads via bf16 MFMA, fused transpose write ----------------
#define YSTRIDE 264
__global__ __launch_bounds__(256) void heads_kernel(float* __restrict__ ws, void* __restrict__ outv){
  const int isf32 = ((const volatile int*)(ws + OFF_FLAG))[0];
  __shared__ unsigned short y[16*YSTRIDE];
  const int t = threadIdx.x;
  const int wave = t >> 6, lane = t & 63;
  const int quad = lane >> 4, l15 = lane & 15;
  const int r0 = blockIdx.x * 16;
  bf16x8 a[8];
  const float* vp = ws + OFF_VP + (r0 + l15)*256;
#pragma unroll
  for (int kt = 0; kt < 8; ++kt) {
    const float4* v4 = (const float4*)(vp + kt*32 + quad*8);
    float4 u0 = v4[0], u1 = v4[1];
    a[kt][0]=(short)f2bf(u0.x); a[kt][1]=(short)f2bf(u0.y); a[kt][2]=(short)f2bf(u0.z); a[kt][3]=(short)f2bf(u0.w);
    a[kt][4]=(short)f2bf(u1.x); a[kt][5]=(short)f2bf(u1.y); a[kt][6]=(short)f2bf(u1.z); a[kt][7]=(short)f2bf(u1.w);
  }
  const bf16x8* HB1 = (const bf16x8*)(ws + OFF_HB1);
#pragma unroll
  for (int nt4 = 0; nt4 < 4; ++nt4) {
    const int nt = wave*4 + nt4;
    const int n = nt*16 + l15;
    const float bias = ws[OFF_HB1B + n];
    f32x4 acc = (f32x4){bias, bias, bias, bias};
#pragma unroll
    for (int kt = 0; kt < 8; ++kt)
      acc = __builtin_amdgcn_mfma_f32_16x16x32_bf16(a[kt], HB1[(nt*8+kt)*64 + lane], acc, 0, 0, 0);
#pragma unroll
    for (int jj = 0; jj < 4; ++jj)
      y[(quad*4+jj)*YSTRIDE + n] = f2bf(fmaxf(acc[jj], 0.f));
  }
  __syncthreads();
#pragma unroll
  for (int kt = 0; kt < 8; ++kt)
    a[kt] = *(const bf16x8*)&y[l15*YSTRIDE + kt*32 + quad*8];
  __syncthreads();
  const bf16x8* HB2 = (const bf16x8*)(ws + OFF_HB2);
#pragma unroll
  for (int nt4 = 0; nt4 < 4; ++nt4) {
    const int nt = wave*4 + nt4;
    const int n = nt*16 + l15;
    const float bias = ws[OFF_HB2B + n];
    f32x4 acc = (f32x4){bias, bias, bias, bias};
#pragma unroll
    for (int kt = 0; kt < 8; ++kt)
      acc = __builtin_amdgcn_mfma_f32_16x16x32_bf16(a[kt], HB2[(nt*8+kt)*64 + lane], acc, 0, 0, 0);
#pragma unroll
    for (int jj = 0; jj < 4; ++jj)
      y[(quad*4+jj)*YSTRIDE + n] = f2bf(fmaxf(acc[jj], 0.f));
  }
  __syncthreads();
#pragma unroll
  for (int kt = 0; kt < 8; ++kt)
    a[kt] = *(const bf16x8*)&y[l15*YSTRIDE + kt*32 + quad*8];
  const bf16x8* HB3 = (const bf16x8*)(ws + OFF_HB3);
  {
    const int n = wave*16 + l15;
    const float bias = ws[OFF_HB3B + n];
    f32x4 acc = (f32x4){bias, bias, bias, bias};
#pragma unroll
    for (int kt = 0; kt < 8; ++kt)
      acc = __builtin_amdgcn_mfma_f32_16x16x32_bf16(a[kt], HB3[(wave*8+kt)*64 + lane], acc, 0, 0, 0);
    if (n < 48) {
#pragma unroll
      for (int jj = 0; jj < 4; ++jj) {
        const int gr = r0 + quad*4 + jj;
        const int b = gr >> 12, rem = gr & 4095, s = rem >> 2, d = rem & 3;
        const int o = ((b*48 + n)*1024 + s)*4 + d;
        if (isf32) ((float*)outv)[o] = acc[jj];
        else       ((__hip_bfloat16*)outv)[o] = __float2bfloat16(acc[jj]);
      }
    }
  }
}

extern "C" void kernel_launch(void* const* d_in, const int* in_sizes, int n_in,
                              void* d_out, int out_size, void* d_ws, size_t ws_size,
                              hipStream_t stream) {
  float* ws = (float*)d_ws;
  Ptrs P;
  for (int i = 0; i < 25; ++i) P.p[i] = d_in[i];
  prep_kernel<<<(PREP_TOTAL+255)/256, 256, 0, stream>>>(P, ws);
  group_kernel<<<NB*NS/2, 256, 0, stream>>>(ws);
  mlp_kernel<<<16384, 256, 0, stream>>>(ws);
  heads_kernel<<<NGROUP/16, 256, 0, stream>>>(ws, d_out);
}

// Round 11
// 200.406 us; speedup vs baseline: 1.3677x; 1.3677x over previous
//
#include <hip/hip_runtime.h>
#include <hip/hip_bf16.h>

// ---------------- problem constants ----------------
#define NB    2
#define NS    1024
#define NPTS  8192
#define NGROUP (NB*NS*4)   // 8192 groups

// ---------------- ws layout (float offsets) ----------------
enum : int {
  OFF_BW2  = 256,      // 8192 bf16: W2 folded, frag order
  OFF_W1Q  = 4352,     // 64 x float4 (w0,w1,w2,b) folded L1
  OFF_B2   = 8448,     // 128 f32
  OFF_BW3  = 8576,     // 32768 bf16: W3 folded, B-frag order
  OFF_B3   = 41344,    // 256 f32
  OFF_HB1  = 41600,    // 65536 bf16 head L1
  OFF_HB1B = 74368,
  OFF_HB2  = 74624,    // 65536 bf16 head L2 block-diag
  OFF_HB2B = 107392,
  OFF_HB3  = 107648,   // 16384 bf16 head L3
  OFF_HB3B = 115840,
  OFF_FEAT = 146688,            // 8192 * 64 * 3
  OFF_VP   = 1719552,           // 8192 * 256
  // overlaid into VP region (dead after group):
  OFF_PCX  = 1719552, OFF_PCY = 1735936, OFF_PCZ = 1752320,
  OFF_SEED = 1768704, OFF_ROT = 1774848,
  OFF_CNT  = 3816704,           // 8192 ints: per-group MT class (1..4), plain stores
  OFF_FLAG = 3824896,           // 1 int
  PREP_TOTAL = 189632 + 6144 + 18432 + 49152,  // = 263360
};

struct Ptrs { const void* p[25]; };

typedef __attribute__((ext_vector_type(8))) short bf16x8;
typedef __attribute__((ext_vector_type(4))) float f32x4;
typedef __attribute__((ext_vector_type(4))) unsigned u32x4;

template<typename T> struct LD;
template<> struct LD<float> {
  static __device__ __forceinline__ float get(const void* p, int i){ return ((const float*)p)[i]; }
};
template<> struct LD<__hip_bfloat16> {
  static __device__ __forceinline__ float get(const void* p, int i){ return __bfloat162float(((const __hip_bfloat16*)p)[i]); }
};

template<typename T>
__device__ __forceinline__ float bnscale(const void* bn, int C, int c){
  float g = LD<T>::get(bn, c);
  float v = LD<T>::get(bn, 3*C + c);
  return g / sqrtf(v + 1e-5f);
}

__device__ __forceinline__ unsigned short f2bf(float v){
  __hip_bfloat16 hb = __float2bfloat16(v);
  return *reinterpret_cast<unsigned short*>(&hb);
}

#if __has_builtin(__builtin_amdgcn_cvt_pk_bf16_f32)
typedef __attribute__((ext_vector_type(2))) __bf16 bf16x2_t;
__device__ __forceinline__ unsigned pk2bf(float a, float b){
  bf16x2_t r = __builtin_amdgcn_cvt_pk_bf16_f32(a, b);
  return *reinterpret_cast<unsigned*>(&r);
}
#else
__device__ __forceinline__ unsigned pk2bf(float a, float b){
  return (unsigned)f2bf(a) | ((unsigned)f2bf(b) << 16);
}
#endif

// ---------------- prep body: fold BN; swizzle weights; fp32 SoA geometry ----------------
template<typename T>
__device__ void prep_body(const Ptrs& in, float* __restrict__ ws, int i){
  if (i < 256) { int c = i>>2, d = i&3; float s = bnscale<T>(in.p[4],64,c);
    float v = (d<3) ? LD<T>::get(in.p[3], c*3+d)*s
                    : LD<T>::get(in.p[4],64+c) - LD<T>::get(in.p[4],2*64+c)*s;
    ws[OFF_W1Q+i] = v; return; }
  i -= 256;
  if (i < 8192) { // BW2: 128x64, KT=2
    int j = i&7, f = i>>3, lane = f&63, kn = f>>6, kt = kn&1, nt = kn>>1;
    int n = nt*16 + (lane&15), k = kt*32 + ((lane>>4)<<3) + j;
    float s = bnscale<T>(in.p[6],128,n);
    ((unsigned short*)(ws + OFF_BW2))[i] = f2bf(LD<T>::get(in.p[5], n*64+k)*s); return; }
  i -= 8192;
  if (i < 32768) { // BW3: 256x128, KT=4
    int j = i&7, f = i>>3, lane = f&63, kn = f>>6, kt = kn&3, nt = kn>>2;
    int n = nt*16 + (lane&15), k = kt*32 + ((lane>>4)<<3) + j;
    float s = bnscale<T>(in.p[8],256,n);
    ((unsigned short*)(ws + OFF_BW3))[i] = f2bf(LD<T>::get(in.p[7], n*128+k)*s); return; }
  i -= 32768;
  if (i < 128) { float s = bnscale<T>(in.p[6],128,i);
    ws[OFF_B2+i] = LD<T>::get(in.p[6],128+i) - LD<T>::get(in.p[6],2*128+i)*s; return; }
  i -= 128;
  if (i < 256) { float s = bnscale<T>(in.p[8],256,i);
    ws[OFF_B3+i] = LD<T>::get(in.p[8],256+i) - LD<T>::get(in.p[8],2*256+i)*s; return; }
  i -= 256;
  if (i < 65536) { // HB1
    int j = i&7, f = i>>3, lane = f&63, kn = f>>6, kt = kn&7, nt = kn>>3;
    int n = nt*16 + (lane&15), k = kt*32 + ((lane>>4)<<3) + j;
    float v;
    if (n < 128) v = LD<T>::get(in.p[9],  n*256+k)       * bnscale<T>(in.p[11],128,n);
    else         v = LD<T>::get(in.p[17], (n-128)*256+k) * bnscale<T>(in.p[19],128,n-128);
    ((unsigned short*)(ws + OFF_HB1))[i] = f2bf(v); return; }
  i -= 65536;
  if (i < 256) { int n = i; float v;
    if (n < 128) { float s = bnscale<T>(in.p[11],128,n);
      v = (LD<T>::get(in.p[10],n) - LD<T>::get(in.p[11],2*128+n))*s + LD<T>::get(in.p[11],128+n); }
    else { int m = n-128; float s = bnscale<T>(in.p[19],128,m);
      v = (LD<T>::get(in.p[18],m) - LD<T>::get(in.p[19],2*128+m))*s + LD<T>::get(in.p[19],128+m); }
    ws[OFF_HB1B+n] = v; return; }
  i -= 256;
  if (i < 65536) { // HB2 block-diagonal
    int j = i&7, f = i>>3, lane = f&63, kn = f>>6, kt = kn&7, nt = kn>>3;
    int n = nt*16 + (lane&15), k = kt*32 + ((lane>>4)<<3) + j;
    float v = 0.f;
    if (n < 128) { if (k < 128)  v = LD<T>::get(in.p[12], n*128+k)            * bnscale<T>(in.p[14],128,n); }
    else         { if (k >= 128) v = LD<T>::get(in.p[20], (n-128)*128+(k-128)) * bnscale<T>(in.p[22],128,n-128); }
    ((unsigned short*)(ws + OFF_HB2))[i] = f2bf(v); return; }
  i -= 65536;
  if (i < 256) { int n = i; float v;
    if (n < 128) { float s = bnscale<T>(in.p[14],128,n);
      v = (LD<T>::get(in.p[13],n) - LD<T>::get(in.p[14],2*128+n))*s + LD<T>::get(in.p[14],128+n); }
    else { int m = n-128; float s = bnscale<T>(in.p[22],128,m);
      v = (LD<T>::get(in.p[21],m) - LD<T>::get(in.p[22],2*128+m))*s + LD<T>::get(in.p[22],128+m); }
    ws[OFF_HB2B+n] = v; return; }
  i -= 256;
  if (i < 16384) { // HB3
    int j = i&7, f = i>>3, lane = f&63, kn = f>>6, kt = kn&7, nt = kn>>3;
    int n = nt*16 + (lane&15), k = kt*32 + ((lane>>4)<<3) + j;
    float v = 0.f;
    if (n < 36)      { if (k < 128)  v = LD<T>::get(in.p[15], n*128+k); }
    else if (n < 48) { if (k >= 128) v = LD<T>::get(in.p[23], (n-36)*128+(k-128)); }
    ((unsigned short*)(ws + OFF_HB3))[i] = f2bf(v); return; }
  i -= 16384;
  if (i < 64) { int n = i; float v = 0.f;
    if (n < 36) v = LD<T>::get(in.p[16], n);
    else if (n < 48) v = LD<T>::get(in.p[24], n-36);
    ws[OFF_HB3B+n] = v; return; }
  i -= 64;
  if (i < 6144)  { ws[OFF_SEED+i] = LD<T>::get(in.p[0], i); return; }
  i -= 6144;
  if (i < 18432) { ws[OFF_ROT+i] = LD<T>::get(in.p[2], i); return; }
  i -= 18432;
  { int arr = i >> 14, idx = i & 16383;
    ws[OFF_PCX + arr*16384 + idx] = LD<T>::get(in.p[1], idx*3 + arr); }
}

// ---------------- kernel 0: detect dtype + prep ----------------
__global__ __launch_bounds__(256) void prep_kernel(Ptrs in, float* __restrict__ ws){
  __shared__ int sf;
  const int t = threadIdx.x;
  if (t == 0) sf = 0;
  __syncthreads();
  int loc = 0;
  const uint4* w3r = (const uint4*)in.p[7];
#pragma unroll
  for (int k = 0; k < 8; ++k) {
    uint4 u = w3r[t + k*256];
    loc |= ((u.x & 0x7F80u) == 0x7F80u) | (((u.x>>16) & 0x7F80u) == 0x7F80u);
    loc |= ((u.y & 0x7F80u) == 0x7F80u) | (((u.y>>16) & 0x7F80u) == 0x7F80u);
    loc |= ((u.z & 0x7F80u) == 0x7F80u) | (((u.z>>16) & 0x7F80u) == 0x7F80u);
    loc |= ((u.w & 0x7F80u) == 0x7F80u) | (((u.w>>16) & 0x7F80u) == 0x7F80u);
  }
  if (loc) atomicOr(&sf, 1);
  __syncthreads();
  const int isf32 = sf;
  const int i = blockIdx.x*256 + t;
  if (i == 0) ((int*)(ws + OFF_FLAG))[0] = isf32;
  if (i >= PREP_TOTAL) return;
  if (isf32) prep_body<float>(in, ws, i);
  else       prep_body<__hip_bfloat16>(in, ws, i);
}

// ---------------- group: 2 seeds/block, 2 waves/seed, fill-to-64 + MT store ----------------
__global__ __launch_bounds__(256) void group_kernel(float* __restrict__ ws){
#pragma clang fp contract(off)
  __shared__ float scratch[2][2][4][192];   // [seed][half][bin][slot*3]
  __shared__ int   cl[2][2][4];
  __shared__ float p0s[2][3];
  const int t = threadIdx.x;
  const int wave = t >> 6, lane = t & 63;
  const int s = wave >> 1, half = wave & 1;
  const int seedIdx = blockIdx.x*2 + s;
  const int b = seedIdx >> 10;
  const float sx = ws[OFF_SEED + seedIdx*3+0];
  const float sy = ws[OFF_SEED + seedIdx*3+1];
  const float sz = ws[OFF_SEED + seedIdx*3+2];
  const float r00=ws[OFF_ROT+seedIdx*9+0], r01=ws[OFF_ROT+seedIdx*9+1], r02=ws[OFF_ROT+seedIdx*9+2];
  const float r10=ws[OFF_ROT+seedIdx*9+3], r11=ws[OFF_ROT+seedIdx*9+4], r12=ws[OFF_ROT+seedIdx*9+5];
  const float r20=ws[OFF_ROT+seedIdx*9+6], r21=ws[OFF_ROT+seedIdx*9+7], r22=ws[OFF_ROT+seedIdx*9+8];
  const float* px = ws + OFF_PCX + b*8192;
  const float* py = ws + OFF_PCY + b*8192;
  const float* pz = ws + OFF_PCZ + b*8192;
  if (half == 0 && lane == 0) {
    float e0 = px[0] - sx, e1 = py[0] - sy, e2 = pz[0] - sz;
    p0s[s][0] = e0*r00 + e1*r10 + e2*r20;
    p0s[s][1] = e0*r01 + e1*r11 + e2*r21;
    p0s[s][2] = e0*r02 + e1*r12 + e2*r22;
  }
  float* s0 = scratch[s][half][0];
  float* s1 = scratch[s][half][1];
  float* s2 = scratch[s][half][2];
  float* s3 = scratch[s][half][3];
  int c0n=0, c1n=0, c2n=0, c3n=0;
  const int basept = half*4096;
  const unsigned long long pm = (1ull << lane) - 1ull;

  auto scan = [&](float x, float y, float z){
    float e0 = x - sx, e1 = y - sy, e2 = z - sz;
    float rx = e0*r00 + e1*r10 + e2*r20;
    float ry = e0*r01 + e1*r11 + e2*r21;
    float rz = e0*r02 + e1*r12 + e2*r22;
    float r2 = ry*ry + rz*rz;
    const bool mb = (rx > -0.2f) && (r2 < 0.09f);
    { bool m = mb && (rx < 0.1f); unsigned long long bal = __ballot(m);
      if (bal) { int slot = c0n + __popcll(bal & pm);
        if (m && slot < 64) { s0[slot*3]=rx; s0[slot*3+1]=ry; s0[slot*3+2]=rz; }
        c0n += __popcll(bal); } }
    { bool m = mb && (rx < 0.2f); unsigned long long bal = __ballot(m);
      if (bal) { int slot = c1n + __popcll(bal & pm);
        if (m && slot < 64) { s1[slot*3]=rx; s1[slot*3+1]=ry; s1[slot*3+2]=rz; }
        c1n += __popcll(bal); } }
    { bool m = mb && (rx < 0.3f); unsigned long long bal = __ballot(m);
      if (bal) { int slot = c2n + __popcll(bal & pm);
        if (m && slot < 64) { s2[slot*3]=rx; s2[slot*3+1]=ry; s2[slot*3+2]=rz; }
        c2n += __popcll(bal); } }
    { bool m = mb && (rx < 0.4f); unsigned long long bal = __ballot(m);
      if (bal) { int slot = c3n + __popcll(bal & pm);
        if (m && slot < 64) { s3[slot*3]=rx; s3[slot*3+1]=ry; s3[slot*3+2]=rz; }
        c3n += __popcll(bal); } }
  };

  for (int c = 0; c < 64; c += 2) {
    const int i0 = basept + c*64 + lane;
    float xA = px[i0],    yA = py[i0],    zA = pz[i0];
    float xB = px[i0+64], yB = py[i0+64], zB = pz[i0+64];
    scan(xA, yA, zA);
    scan(xB, yB, zB);
  }
  if (lane == 0) { cl[s][half][0]=c0n; cl[s][half][1]=c1n; cl[s][half][2]=c2n; cl[s][half][3]=c3n; }
  __syncthreads();
  // merge + fill all 64 slots
  for (int idx = t; idx < 512; idx += 256) {
    const int ss = idx >> 8, bin = (idx >> 6) & 3, slot = idx & 63;
    int ca = cl[ss][0][bin]; if (ca > 64) ca = 64;
    int cb = cl[ss][1][bin];
    const float* A = scratch[ss][0][bin];
    const float* B = scratch[ss][1][bin];
    float fx, fy, fz;
    if (slot < ca)              { fx=A[slot*3]; fy=A[slot*3+1]; fz=A[slot*3+2]; }
    else if (slot - ca < cb)    { int q = slot-ca; fx=B[q*3]; fy=B[q*3+1]; fz=B[q*3+2]; }
    else if (ca > 0)            { fx=A[0]; fy=A[1]; fz=A[2]; }
    else if (cb > 0)            { fx=B[0]; fy=B[1]; fz=B[2]; }
    else                        { fx=p0s[ss][0]; fy=p0s[ss][1]; fz=p0s[ss][2]; }
    const int g = (blockIdx.x*2 + ss)*4 + bin;
    float* fo = ws + OFF_FEAT + g*192;
    fo[slot*3+0]=fx; fo[slot*3+1]=fy; fo[slot*3+2]=fz;
  }
  // per-group MT class (1..4): plain store, no atomics
  if (t < 8) {
    const int ss = t >> 2, bin = t & 3;
    int tot = cl[ss][0][bin] + cl[ss][1][bin];
    if (tot > 64) tot = 64;
    if (tot < 1)  tot = 1;
    const int g = (blockIdx.x*2 + ss)*4 + bin;
    ((int*)(ws + OFF_CNT))[g] = (tot + 15) >> 4;
  }
}

// ---------------- mlp body: MTS sample-tiles (static), role-swapped L2 ----------------
template<int MTS>
__device__ __forceinline__ void mlp_body(float* __restrict__ ws, unsigned short* __restrict__ h2,
                                         const float* __restrict__ wq,
                                         int lane, int quad, int l15, int nhalf, int g){
  const float* feat = ws + OFF_FEAT + g*192;
  float fx[MTS], fy[MTS], fz[MTS];
#pragma unroll
  for (int Nt = 0; Nt < MTS; ++Nt) {
    const int sm = Nt*16 + l15;
    fx[Nt] = feat[sm*3+0]; fy[Nt] = feat[sm*3+1]; fz[Nt] = feat[sm*3+2];
  }
  bf16x8 b1[MTS][2];
#pragma unroll
  for (int kt = 0; kt < 2; ++kt) {
    f32x4 w[8];
#pragma unroll
    for (int j = 0; j < 8; ++j) w[j] = *(const f32x4*)(wq + (kt*32 + quad*8 + j)*4);
#pragma unroll
    for (int Nt = 0; Nt < MTS; ++Nt) {
      const float x0 = fx[Nt], x1 = fy[Nt], x2 = fz[Nt];
      u32x4 p;
#pragma unroll
      for (int jp = 0; jp < 4; ++jp) {
        const f32x4 wa = w[2*jp], wb = w[2*jp+1];
        const float v0 = fmaxf(wa[3] + x0*wa[0] + x1*wa[1] + x2*wa[2], 0.f);
        const float v1 = fmaxf(wb[3] + x0*wb[0] + x1*wb[1] + x2*wb[2], 0.f);
        p[jp] = pk2bf(v0, v1);
      }
      b1[Nt][kt] = __builtin_bit_cast(bf16x8, p);
    }
  }
  const bf16x8* BW2 = (const bf16x8*)(ws + OFF_BW2);
#pragma unroll
  for (int mt4 = 0; mt4 < 4; ++mt4) {
    const int Mt = nhalf*4 + mt4;
    const f32x4 bias4 = *(const f32x4*)(ws + OFF_B2 + Mt*16 + quad*4);
    f32x4 acc[MTS];
#pragma unroll
    for (int Nt = 0; Nt < MTS; ++Nt) acc[Nt] = bias4;
#pragma unroll
    for (int kt = 0; kt < 2; ++kt) {
      const bf16x8 aw = BW2[(Mt*2+kt)*64 + lane];
#pragma unroll
      for (int Nt = 0; Nt < MTS; ++Nt)
        acc[Nt] = __builtin_amdgcn_mfma_f32_16x16x32_bf16(aw, b1[Nt][kt], acc[Nt], 0, 0, 0);
    }
#pragma unroll
    for (int Nt = 0; Nt < MTS; ++Nt) {
      const unsigned lo = pk2bf(fmaxf(acc[Nt][0],0.f), fmaxf(acc[Nt][1],0.f));
      const unsigned hi = pk2bf(fmaxf(acc[Nt][2],0.f), fmaxf(acc[Nt][3],0.f));
      uint2* dst = (uint2*)&h2[(Nt*16 + l15)*136 + Mt*16 + quad*4];
      *dst = make_uint2(lo, hi);
    }
  }
  __syncthreads();
  bf16x8 a2[MTS][4];
#pragma unroll
  for (int mt = 0; mt < MTS; ++mt)
#pragma unroll
    for (int kt = 0; kt < 4; ++kt)
      a2[mt][kt] = *(const bf16x8*)&h2[(mt*16 + l15)*136 + kt*32 + quad*8];
  const bf16x8* BW3 = (const bf16x8*)(ws + OFF_BW3);
  float vpv[8];
#pragma unroll
  for (int nt8 = 0; nt8 < 8; ++nt8) {
    const int nt = nhalf*8 + nt8;
    const int n = nt*16 + l15;
    const float bias = ws[OFF_B3 + n];
    f32x4 acc[MTS];
#pragma unroll
    for (int mt = 0; mt < MTS; ++mt) acc[mt] = (f32x4){bias, bias, bias, bias};
#pragma unroll
    for (int kt = 0; kt < 4; ++kt) {
      const bf16x8 b = BW3[(nt*4+kt)*64 + lane];
#pragma unroll
      for (int mt = 0; mt < MTS; ++mt)
        acc[mt] = __builtin_amdgcn_mfma_f32_16x16x32_bf16(a2[mt][kt], b, acc[mt], 0, 0, 0);
    }
    float mx = 0.f;   // rows [V, MTS*16) are fill duplicates; relu >= 0
#pragma unroll
    for (int mt = 0; mt < MTS; ++mt)
      mx = fmaxf(mx, fmaxf(fmaxf(acc[mt][0], acc[mt][1]), fmaxf(acc[mt][2], acc[mt][3])));
    mx = fmaxf(mx, __shfl_xor(mx, 16, 64));
    mx = fmaxf(mx, __shfl_xor(mx, 32, 64));
    vpv[nt8] = mx;
  }
  if (quad == 0) {
    float* vp = ws + OFF_VP + g*256 + nhalf*128;
#pragma unroll
    for (int nt8 = 0; nt8 < 8; ++nt8) vp[nt8*16 + l15] = vpv[nt8];
  }
}

// ---------------- kernel 2: SharedMLP, block-uniform static-MT dispatch ----------------
// One block per adjacent pair (g0=2*blk, g1=2*blk+1). Variant = max(mt0, mt1):
// single top-level uniform switch into fully-static bodies — no per-MFMA guards,
// no worklists, no atomics.
__global__ __launch_bounds__(256) void mlp_kernel(float* __restrict__ ws){
  __shared__ unsigned short h2s[2][64*136];
  __shared__ float w1q[4][256];
  const int blk = blockIdx.x;
  const int g0 = blk*2, g1 = blk*2 + 1;
  const int* cnt = (const int*)(ws + OFF_CNT);
  const int mt0 = cnt[g0], mt1 = cnt[g1];
  const int v = (mt0 > mt1) ? mt0 : mt1;     // 1..4
  const int t = threadIdx.x;
  const int wave = t >> 6, lane = t & 63;
  const int quad = lane >> 4, l15 = lane & 15;
  const int grp = wave >> 1, nhalf = wave & 1;
  const int g = grp ? g1 : g0;
  for (int i = t; i < 1024; i += 256) w1q[i>>8][i&255] = ws[OFF_W1Q + (i&255)];
  __syncthreads();
  unsigned short* h2 = h2s[grp];
  const float* wq = w1q[quad];
  switch (v) {
    case 1:  mlp_body<1>(ws, h2, wq, lane, quad, l15, nhalf, g); break;
    case 2:  mlp_body<2>(ws, h2, wq, lane, quad, l15, nhalf, g); break;
    case 3:  mlp_body<3>(ws, h2, wq, lane, quad, l15, nhalf, g); break;
    default: mlp_body<4>(ws, h2, wq, lane, quad, l15, nhalf, g); break;
  }
}

// ---------------- kernel 3: heads via bf16 MFMA, fused transpose write ----------------
#define YSTRIDE 264
__global__ __launch_bounds__(256) void heads_kernel(float* __restrict__ ws, void* __restrict__ outv){
  const int isf32 = ((const volatile int*)(ws + OFF_FLAG))[0];
  __shared__ unsigned short y[16*YSTRIDE];
  const int t = threadIdx.x;
  const int wave = t >> 6, lane = t & 63;
  const int quad = lane >> 4, l15 = lane & 15;
  const int r0 = blockIdx.x * 16;
  bf16x8 a[8];
  const float* vp = ws + OFF_VP + (r0 + l15)*256;
#pragma unroll
  for (int kt = 0; kt < 8; ++kt) {
    const float4* v4 = (const float4*)(vp + kt*32 + quad*8);
    float4 u0 = v4[0], u1 = v4[1];
    a[kt][0]=(short)f2bf(u0.x); a[kt][1]=(short)f2bf(u0.y); a[kt][2]=(short)f2bf(u0.z); a[kt][3]=(short)f2bf(u0.w);
    a[kt][4]=(short)f2bf(u1.x); a[kt][5]=(short)f2bf(u1.y); a[kt][6]=(short)f2bf(u1.z); a[kt][7]=(short)f2bf(u1.w);
  }
  const bf16x8* HB1 = (const bf16x8*)(ws + OFF_HB1);
#pragma unroll
  for (int nt4 = 0; nt4 < 4; ++nt4) {
    const int nt = wave*4 + nt4;
    const int n = nt*16 + l15;
    const float bias = ws[OFF_HB1B + n];
    f32x4 acc = (f32x4){bias, bias, bias, bias};
#pragma unroll
    for (int kt = 0; kt < 8; ++kt)
      acc = __builtin_amdgcn_mfma_f32_16x16x32_bf16(a[kt], HB1[(nt*8+kt)*64 + lane], acc, 0, 0, 0);
#pragma unroll
    for (int jj = 0; jj < 4; ++jj)
      y[(quad*4+jj)*YSTRIDE + n] = f2bf(fmaxf(acc[jj], 0.f));
  }
  __syncthreads();
#pragma unroll
  for (int kt = 0; kt < 8; ++kt)
    a[kt] = *(const bf16x8*)&y[l15*YSTRIDE + kt*32 + quad*8];
  __syncthreads();
  const bf16x8* HB2 = (const bf16x8*)(ws + OFF_HB2);
#pragma unroll
  for (int nt4 = 0; nt4 < 4; ++nt4) {
    const int nt = wave*4 + nt4;
    const int n = nt*16 + l15;
    const float bias = ws[OFF_HB2B + n];
    f32x4 acc = (f32x4){bias, bias, bias, bias};
#pragma unroll
    for (int kt = 0; kt < 8; ++kt)
      acc = __builtin_amdgcn_mfma_f32_16x16x32_bf16(a[kt], HB2[(nt*8+kt)*64 + lane], acc, 0, 0, 0);
#pragma unroll
    for (int jj = 0; jj < 4; ++jj)
      y[(quad*4+jj)*YSTRIDE + n] = f2bf(fmaxf(acc[jj], 0.f));
  }
  __syncthreads();
#pragma unroll
  for (int kt = 0; kt < 8; ++kt)
    a[kt] = *(const bf16x8*)&y[l15*YSTRIDE + kt*32 + quad*8];
  const bf16x8* HB3 = (const bf16x8*)(ws + OFF_HB3);
  {
    const int n = wave*16 + l15;
    const float bias = ws[OFF_HB3B + n];
    f32x4 acc = (f32x4){bias, bias, bias, bias};
#pragma unroll
    for (int kt = 0; kt < 8; ++kt)
      acc = __builtin_amdgcn_mfma_f32_16x16x32_bf16(a[kt], HB3[(wave*8+kt)*64 + lane], acc, 0, 0, 0);
    if (n < 48) {
#pragma unroll
      for (int jj = 0; jj < 4; ++jj) {
        const int gr = r0 + quad*4 + jj;
        const int b = gr >> 12, rem = gr & 4095, s = rem >> 2, d = rem & 3;
        const int o = ((b*48 + n)*1024 + s)*4 + d;
        if (isf32) ((float*)outv)[o] = acc[jj];
        else       ((__hip_bfloat16*)outv)[o] = __float2bfloat16(acc[jj]);
      }
    }
  }
}

extern "C" void kernel_launch(void* const* d_in, const int* in_sizes, int n_in,
                              void* d_out, int out_size, void* d_ws, size_t ws_size,
                              hipStream_t stream) {
  float* ws = (float*)d_ws;
  Ptrs P;
  for (int i = 0; i < 25; ++i) P.p[i] = d_in[i];
  prep_kernel<<<(PREP_TOTAL+255)/256, 256, 0, stream>>>(P, ws);
  group_kernel<<<NB*NS/2, 256, 0, stream>>>(ws);
  mlp_kernel<<<NGROUP/2, 256, 0, stream>>>(ws);
  heads_kernel<<<NGROUP/16, 256, 0, stream>>>(ws, d_out);
}